// Round 7
// baseline (242.566 us; speedup 1.0000x reference)
//
#include <hip/hip_runtime.h>

#define NN 50000
#define NPAD 50048           // 782 * 64 (featb rows, tail zeroed)
#define NE 500000
#define DD 128
#define NTILE 782            // ceil(NN/64)
#define OFFS_PAD 50176       // 49*1024, >= NN+1

// ALPHA = 0.5 → both sqrt(ALPHA) and sqrt(1-ALPHA) are sqrt(0.5).
__device__ __constant__ float SQ_A = 0.70710678118654752440f;

typedef __attribute__((ext_vector_type(8))) short short8;
typedef __attribute__((ext_vector_type(4))) float float4v;

// float → bf16 bits, round-to-nearest-even.
__device__ inline ushort f2bf(float f)
{
    uint u = __float_as_uint(f);
    u += 0x7fffu + ((u >> 16) & 1u);
    return (ushort)(u >> 16);
}
__device__ inline uint pk2(float a, float b)
{
    return (uint)f2bf(a) | ((uint)f2bf(b) << 16);
}
__device__ inline float bf_lo(uint d) { return __uint_as_float(d << 16); }
__device__ inline float bf_hi(uint d) { return __uint_as_float(d & 0xffff0000u); }

// ---------------------------------------------------------------------------
// Prep: feat fp32 → featb bf16 [NPAD][128] (rows >= NN zeroed);
//       W/loop_w → wtb bf16 [3][prow=128][k=128], scaled by sqrt(.5) and
//       ROW-PERMUTED so that B-frag row mq of tile nt holds actual column
//       col0 + 2*mq + nt  → epilogue lanes own ADJACENT cols → packed stores.
//       prow(c) = (c>>5)*32 + (c&1)*16 + ((c&31)>>1).
//       zero offs[OFFS_PAD].
// ---------------------------------------------------------------------------
#define PREP_FEAT (NPAD * 16)        // 16 chunks of 8 elems per row
#define PREP_WTB  (3 * 2048)         // per seg: 16 k-chunks * 128 cols
#define PREP_ZERO (OFFS_PAD / 4)
#define PREP_TASKS (PREP_FEAT + PREP_WTB + PREP_ZERO)

__global__ __launch_bounds__(256)
void prep_kernel(const float* __restrict__ feat,
                 const float* __restrict__ weight,
                 const float* __restrict__ loop_w,
                 ushort* __restrict__ featb,
                 ushort* __restrict__ wtb,
                 int* __restrict__ offs)
{
    int t = blockIdx.x * 256 + threadIdx.x;
    if (t < PREP_FEAT) {
        int row = t >> 4;
        int c   = t & 15;            // k-chunk: elems c*8 .. c*8+7
        float4 v0 = make_float4(0.f, 0.f, 0.f, 0.f), v1 = v0;
        if (row < NN) {
            const float4* p = (const float4*)(feat + (size_t)row * DD + c * 8);
            v0 = p[0]; v1 = p[1];
        }
        uint4 pk;
        pk.x = pk2(v0.x, v0.y); pk.y = pk2(v0.z, v0.w);
        pk.z = pk2(v1.x, v1.y); pk.w = pk2(v1.z, v1.w);
        *(uint4*)&featb[(size_t)row * DD + c * 8] = pk;
    } else if (t < PREP_FEAT + PREP_WTB) {
        int u   = t - PREP_FEAT;
        int seg = u >> 11;           // 0,1 → relations; 2 → loop
        int c   = (u >> 7) & 15;     // k-chunk
        int col = u & 127;           // actual output column
        const float* wsrc = (seg < 2) ? (weight + (size_t)seg * DD * DD)
                                      : loop_w;
        float v[8];
#pragma unroll
        for (int j = 0; j < 8; ++j)
            v[j] = wsrc[(size_t)(c * 8 + j) * DD + col] * SQ_A;
        uint4 pk;
        pk.x = pk2(v[0], v[1]); pk.y = pk2(v[2], v[3]);
        pk.z = pk2(v[4], v[5]); pk.w = pk2(v[6], v[7]);
        int prow = (col >> 5) * 32 + ((col & 1) << 4) + ((col & 31) >> 1);
        *(uint4*)&wtb[((size_t)seg * DD + prow) * DD + c * 8] = pk;
    } else if (t < PREP_TASKS) {
        int u = t - (PREP_FEAT + PREP_WTB);
        ((int4*)offs)[u] = make_int4(0, 0, 0, 0);
    }
}

// ---------------------------------------------------------------------------
// Histogram (separate: measured faster than folding into transform).
// ---------------------------------------------------------------------------
__global__ __launch_bounds__(256)
void hist_kernel(const int* __restrict__ dst, int* __restrict__ offs)
{
    int e = blockIdx.x * 256 + threadIdx.x;
    if (e < NE) atomicAdd(&offs[dst[e]], 1);
}

// ---------------------------------------------------------------------------
// Transform: ONE block per 64-node tile computes ALL THREE segs.
// A-frags (16×b128) loaded once from featb, reused across the 3 B-panels.
// wtb rows permuted (see prep) → lane mq owns adjacent cols 2mq,2mq+1 →
// epilogue: 16× packed-uint stores (hrelb) / 16× float2 stores (out).
//   seg 0/1 → hrelb[r] (bf16, sqrt(a) folded into wtb)
//   seg 2   → out = bias + loop message (fp32)
// ---------------------------------------------------------------------------
__global__ __launch_bounds__(256, 3)
void transform_mfma_kernel(const ushort* __restrict__ featb,
                           const ushort* __restrict__ wtb,
                           const float* __restrict__ h_bias,
                           ushort* __restrict__ hrelb,
                           float* __restrict__ out)
{
    const int tile  = blockIdx.x;
    const int node0 = tile * 64;
    const int wv    = threadIdx.x >> 6;
    const int lane  = threadIdx.x & 63;
    const int mq    = lane & 15;
    const int quad  = lane >> 4;
    const int col0  = wv * 32;

    // Load all A fragments once: A[m=mq][k=quad*8+j] per (mt, ks).
    short8 afrag[4][4];
#pragma unroll
    for (int mt = 0; mt < 4; ++mt) {
        const ushort* arow = featb + (size_t)(node0 + mt * 16 + mq) * DD;
#pragma unroll
        for (int ks = 0; ks < 4; ++ks)
            afrag[mt][ks] = *(const short8*)&arow[ks * 32 + quad * 8];
    }

#pragma unroll 1
    for (int seg = 0; seg < 3; ++seg) {
        const ushort* wseg = wtb + (size_t)seg * DD * DD;

        short8 bfrag[2][4];
#pragma unroll
        for (int nt = 0; nt < 2; ++nt)
#pragma unroll
            for (int ks = 0; ks < 4; ++ks)
                bfrag[nt][ks] = *(const short8*)
                    &wseg[(size_t)(col0 + nt * 16 + mq) * DD + ks * 32 + quad * 8];

        float4v acc[4][2];
#pragma unroll
        for (int mt = 0; mt < 4; ++mt)
#pragma unroll
            for (int nt = 0; nt < 2; ++nt)
                acc[mt][nt] = (float4v){0.f, 0.f, 0.f, 0.f};

#pragma unroll
        for (int mt = 0; mt < 4; ++mt)
#pragma unroll
            for (int ks = 0; ks < 4; ++ks)
#pragma unroll
                for (int nt = 0; nt < 2; ++nt)
                    acc[mt][nt] = __builtin_amdgcn_mfma_f32_16x16x32_bf16(
                        afrag[mt][ks], bfrag[nt][ks], acc[mt][nt], 0, 0, 0);

        // Epilogue. D: row = quad*4 + r; lane mq owns cols col0+2mq, +1.
        if (seg < 2) {
            ushort* hb = hrelb + (size_t)seg * NN * DD;
#pragma unroll
            for (int mt = 0; mt < 4; ++mt) {
#pragma unroll
                for (int r = 0; r < 4; ++r) {
                    int node = node0 + mt * 16 + quad * 4 + r;
                    if (node < NN) {
                        uint pk = pk2(acc[mt][0][r], acc[mt][1][r]);
                        *(uint*)&hb[(size_t)node * DD + col0 + 2 * mq] = pk;
                    }
                }
            }
        } else {
            float2 bv = *(const float2*)&h_bias[col0 + 2 * mq];
#pragma unroll
            for (int mt = 0; mt < 4; ++mt) {
#pragma unroll
                for (int r = 0; r < 4; ++r) {
                    int node = node0 + mt * 16 + quad * 4 + r;
                    if (node < NN) {
                        float2 v = make_float2(acc[mt][0][r] + bv.x,
                                               acc[mt][1][r] + bv.y);
                        *(float2*)&out[(size_t)node * DD + col0 + 2 * mq] = v;
                    }
                }
            }
        }
    }
}

// ---------------------------------------------------------------------------
// Fused exclusive scan of offs[0..OFFS_PAD) in ONE block (1024 threads,
// 49 rounds). Carry kept in registers (identical in all threads). Also
// writes cursor[i] = excl for i < NN.
// ---------------------------------------------------------------------------
__global__ __launch_bounds__(1024)
void scan_kernel(int* __restrict__ offs, int* __restrict__ cursor)
{
    __shared__ int ws[2][16];
    const int lane = threadIdx.x & 63;
    const int wvi  = threadIdx.x >> 6;
    int carry = 0;
    for (int r = 0; r < 49; ++r) {
        int i = r * 1024 + threadIdx.x;
        int v = offs[i];
        int inc = v;
#pragma unroll
        for (int d = 1; d < 64; d <<= 1) {
            int t = __shfl_up(inc, d, 64);
            if (lane >= d) inc += t;
        }
        if (lane == 63) ws[r & 1][wvi] = inc;
        __syncthreads();
        int wbase = 0, total = 0;
#pragma unroll
        for (int w = 0; w < 16; ++w) {
            int s = ws[r & 1][w];
            total += s;
            if (w < wvi) wbase += s;
        }
        int excl = carry + wbase + inc - v;
        offs[i] = excl;                 // i == NN gets total (=NE) ✓
        if (i < NN) cursor[i] = excl;
        carry += total;
    }
}

// payload[p] = ety*NN + src  → direct hrelb row index for gather.
__global__ __launch_bounds__(256)
void place_kernel(const int* __restrict__ src, const int* __restrict__ dst,
                  const int* __restrict__ ety,
                  int* __restrict__ cursor, int* __restrict__ payload)
{
    int e = blockIdx.x * 256 + threadIdx.x;
    if (e >= NE) return;
    int p = atomicAdd(&cursor[dst[e]], 1);
    payload[p] = ety[e] * NN + src[e];
}

// ---------------------------------------------------------------------------
// Gather: one wave per node; bf16 messages, fp32 accumulate, 4 loads in
// flight. acc starts at out[n] (= bias + loop message).
// ---------------------------------------------------------------------------
__global__ __launch_bounds__(256)
void gather_kernel(const int* __restrict__ offs, const int* __restrict__ payload,
                   const ushort* __restrict__ hrelb, float* __restrict__ out)
{
    const int n = blockIdx.x * 4 + (threadIdx.x >> 6);
    if (n >= NN) return;
    const int lane = threadIdx.x & 63;
    const int e0 = offs[n];
    const int e1 = offs[n + 1];
    float* orow = out + (size_t)n * DD;
    float2 a0 = ((float2*)orow)[lane];
    float2 a1 = make_float2(0.f, 0.f);
    float2 a2 = make_float2(0.f, 0.f);
    float2 a3 = make_float2(0.f, 0.f);
    int e = e0;
    for (; e + 4 <= e1; e += 4) {
        int p0 = payload[e],     p1 = payload[e + 1];
        int p2 = payload[e + 2], p3 = payload[e + 3];
        uint d0 = *(const uint*)&hrelb[(size_t)p0 * DD + lane * 2];
        uint d1 = *(const uint*)&hrelb[(size_t)p1 * DD + lane * 2];
        uint d2 = *(const uint*)&hrelb[(size_t)p2 * DD + lane * 2];
        uint d3 = *(const uint*)&hrelb[(size_t)p3 * DD + lane * 2];
        a0.x += bf_lo(d0); a0.y += bf_hi(d0);
        a1.x += bf_lo(d1); a1.y += bf_hi(d1);
        a2.x += bf_lo(d2); a2.y += bf_hi(d2);
        a3.x += bf_lo(d3); a3.y += bf_hi(d3);
    }
    for (; e < e1; ++e) {
        int p0 = payload[e];
        uint d0 = *(const uint*)&hrelb[(size_t)p0 * DD + lane * 2];
        a0.x += bf_lo(d0); a0.y += bf_hi(d0);
    }
    a0.x += a1.x + a2.x + a3.x;
    a0.y += a1.y + a2.y + a3.y;
    ((float2*)orow)[lane] = a0;
}

// ---------------------------------------------------------------------------
// Tier-2 fallback: atomic scatter from bf16 hrelb.
// ---------------------------------------------------------------------------
__global__ __launch_bounds__(256)
void scatter_kernel(const int* __restrict__ src, const int* __restrict__ dst,
                    const int* __restrict__ ety,
                    const ushort* __restrict__ hrelb,
                    float* __restrict__ out)
{
    const int e = blockIdx.x * 4 + (threadIdx.x >> 6);
    if (e >= NE) return;
    const int lane = threadIdx.x & 63;
    uint d0 = *(const uint*)&hrelb[
        ((size_t)ety[e] * NN + src[e]) * DD + lane * 2];
    float* o = out + (size_t)dst[e] * DD + lane * 2;
    atomicAdd(o,     bf_lo(d0));
    atomicAdd(o + 1, bf_hi(d0));
}

// Tier-3 fallback: fp32 out-init (loop message + bias) + fused per-edge matvec.
__global__ __launch_bounds__(256)
void loop_init_kernel(const float* __restrict__ feat,
                      const float* __restrict__ loop_weight,
                      const float* __restrict__ h_bias,
                      float* __restrict__ out)
{
    const int n = blockIdx.x * 4 + (threadIdx.x >> 6);
    if (n >= NN) return;
    const int lane = threadIdx.x & 63;
    const float2 fv = ((const float2*)(feat + (size_t)n * DD))[lane];
    float a0 = h_bias[lane], a1 = h_bias[lane + 64];
    for (int k = 0; k < 64; ++k) {
        float f0 = __shfl(fv.x, k, 64);
        float f1 = __shfl(fv.y, k, 64);
        a0 += SQ_A * (f0 * loop_weight[(size_t)(2 * k) * DD + lane]
                    + f1 * loop_weight[(size_t)(2 * k + 1) * DD + lane]);
        a1 += SQ_A * (f0 * loop_weight[(size_t)(2 * k) * DD + lane + 64]
                    + f1 * loop_weight[(size_t)(2 * k + 1) * DD + lane + 64]);
    }
    out[(size_t)n * DD + lane] = a0;
    out[(size_t)n * DD + lane + 64] = a1;
}

__global__ __launch_bounds__(256)
void fused_edge_kernel(const float* __restrict__ feat,
                       const int* __restrict__ src, const int* __restrict__ dst,
                       const int* __restrict__ ety,
                       const float* __restrict__ weight,
                       float* __restrict__ out)
{
    const int wave  = threadIdx.x >> 6;
    const int lane  = threadIdx.x & 63;
    const int nwav  = gridDim.x * 4;
    for (int e = blockIdx.x * 4 + wave; e < NE; e += nwav) {
        const int s = src[e];
        const int d = dst[e];
        const int r = ety[e];
        const float2 fv = ((const float2*)(feat + (size_t)s * DD))[lane];
        const float* W = weight + (size_t)r * DD * DD;
        float a0 = 0.f, a1 = 0.f;
        for (int k = 0; k < 64; ++k) {
            float f0 = __shfl(fv.x, k, 64);
            float f1 = __shfl(fv.y, k, 64);
            a0 += f0 * W[(size_t)(2 * k) * DD + lane]
                + f1 * W[(size_t)(2 * k + 1) * DD + lane];
            a1 += f0 * W[(size_t)(2 * k) * DD + lane + 64]
                + f1 * W[(size_t)(2 * k + 1) * DD + lane + 64];
        }
        atomicAdd(out + (size_t)d * DD + lane,      SQ_A * a0);
        atomicAdd(out + (size_t)d * DD + lane + 64, SQ_A * a1);
    }
}

extern "C" void kernel_launch(void* const* d_in, const int* in_sizes, int n_in,
                              void* d_out, int out_size, void* d_ws, size_t ws_size,
                              hipStream_t stream)
{
    const float* feat   = (const float*)d_in[0];
    const int*   src    = (const int*)d_in[1];
    const int*   dst    = (const int*)d_in[2];
    const int*   ety    = (const int*)d_in[3];
    const float* weight = (const float*)d_in[4];
    const float* loop_w = (const float*)d_in[5];
    const float* h_bias = (const float*)d_in[6];
    float* out  = (float*)d_out;

    // Workspace layout (all sections 16B-multiple sized).
    char* p = (char*)d_ws;
    ushort* featb = (ushort*)p;  p += (size_t)NPAD * DD * 2;    // 12.81 MB
    ushort* wtb   = (ushort*)p;  p += (size_t)3 * DD * DD * 2;  // 96 KB
    ushort* hrelb = (ushort*)p;  p += (size_t)2 * NN * DD * 2;  // 25.6 MB
    int* offs     = (int*)p;     p += (size_t)OFFS_PAD * 4;
    const size_t need_t2 = (size_t)(p - (char*)d_ws);
    int* cursor   = (int*)p;     p += (size_t)OFFS_PAD * 4;
    int* payload  = (int*)p;     p += (size_t)NE * 4;
    const size_t need_full = (size_t)(p - (char*)d_ws);         // ~41.2 MB

    if (ws_size >= need_full) {
        prep_kernel<<<(PREP_TASKS + 255) / 256, 256, 0, stream>>>(
            feat, weight, loop_w, featb, wtb, offs);
        hist_kernel<<<(NE + 255) / 256, 256, 0, stream>>>(dst, offs);
        transform_mfma_kernel<<<NTILE, 256, 0, stream>>>(
            featb, wtb, h_bias, hrelb, out);
        scan_kernel<<<1, 1024, 0, stream>>>(offs, cursor);
        place_kernel<<<(NE + 255) / 256, 256, 0, stream>>>(
            src, dst, ety, cursor, payload);
        gather_kernel<<<(NN + 3) / 4, 256, 0, stream>>>(
            offs, payload, hrelb, out);
    } else if (ws_size >= need_t2) {
        prep_kernel<<<(PREP_TASKS + 255) / 256, 256, 0, stream>>>(
            feat, weight, loop_w, featb, wtb, offs);
        transform_mfma_kernel<<<NTILE, 256, 0, stream>>>(
            featb, wtb, h_bias, hrelb, out);
        scatter_kernel<<<dim3((NE + 3) / 4), 256, 0, stream>>>(
            src, dst, ety, hrelb, out);
    } else {
        loop_init_kernel<<<(NN + 3) / 4, 256, 0, stream>>>(
            feat, loop_w, h_bias, out);
        fused_edge_kernel<<<dim3(2048), 256, 0, stream>>>(
            feat, src, dst, ety, weight, out);
    }
}

// Round 8
// 205.388 us; speedup vs baseline: 1.1810x; 1.1810x over previous
//
#include <hip/hip_runtime.h>

#define NN 50000
#define NPAD 50048           // 782 * 64 (featb rows, tail zeroed)
#define NE 500000
#define DD 128
#define NTILE 782            // ceil(NN/64)
#define OFFS_PAD 50176       // 49*1024, >= NN+1

// ALPHA = 0.5 → both sqrt(ALPHA) and sqrt(1-ALPHA) are sqrt(0.5).
__device__ __constant__ float SQ_A = 0.70710678118654752440f;

typedef __attribute__((ext_vector_type(8))) short short8;
typedef __attribute__((ext_vector_type(4))) float float4v;

// float → bf16 bits, round-to-nearest-even.
__device__ inline ushort f2bf(float f)
{
    uint u = __float_as_uint(f);
    u += 0x7fffu + ((u >> 16) & 1u);
    return (ushort)(u >> 16);
}
__device__ inline uint pk2(float a, float b)
{
    return (uint)f2bf(a) | ((uint)f2bf(b) << 16);
}
__device__ inline float bf_lo(uint d) { return __uint_as_float(d << 16); }
__device__ inline float bf_hi(uint d) { return __uint_as_float(d & 0xffff0000u); }

// ---------------------------------------------------------------------------
// Prep: feat fp32 → featb bf16 [NPAD][128] (rows >= NN zeroed);
//       W/loop_w → wtb bf16 [3][prow=128][k=128], scaled by sqrt(.5) and
//       ROW-PERMUTED so that B-frag row mq of tile nt holds actual column
//       col0 + 2*mq + nt  → epilogue lanes own ADJACENT cols → packed stores.
//       prow(c) = (c>>5)*32 + (c&1)*16 + ((c&31)>>1).
//       zero offs[OFFS_PAD].
// ---------------------------------------------------------------------------
#define PREP_FEAT (NPAD * 16)        // 16 chunks of 8 elems per row
#define PREP_WTB  (3 * 2048)         // per seg: 16 k-chunks * 128 cols
#define PREP_ZERO (OFFS_PAD / 4)
#define PREP_TASKS (PREP_FEAT + PREP_WTB + PREP_ZERO)

__global__ __launch_bounds__(256)
void prep_kernel(const float* __restrict__ feat,
                 const float* __restrict__ weight,
                 const float* __restrict__ loop_w,
                 ushort* __restrict__ featb,
                 ushort* __restrict__ wtb,
                 int* __restrict__ offs)
{
    int t = blockIdx.x * 256 + threadIdx.x;
    if (t < PREP_FEAT) {
        int row = t >> 4;
        int c   = t & 15;            // k-chunk: elems c*8 .. c*8+7
        float4 v0 = make_float4(0.f, 0.f, 0.f, 0.f), v1 = v0;
        if (row < NN) {
            const float4* p = (const float4*)(feat + (size_t)row * DD + c * 8);
            v0 = p[0]; v1 = p[1];
        }
        uint4 pk;
        pk.x = pk2(v0.x, v0.y); pk.y = pk2(v0.z, v0.w);
        pk.z = pk2(v1.x, v1.y); pk.w = pk2(v1.z, v1.w);
        *(uint4*)&featb[(size_t)row * DD + c * 8] = pk;
    } else if (t < PREP_FEAT + PREP_WTB) {
        int u   = t - PREP_FEAT;
        int seg = u >> 11;           // 0,1 → relations; 2 → loop
        int c   = (u >> 7) & 15;     // k-chunk
        int col = u & 127;           // actual output column
        const float* wsrc = (seg < 2) ? (weight + (size_t)seg * DD * DD)
                                      : loop_w;
        float v[8];
#pragma unroll
        for (int j = 0; j < 8; ++j)
            v[j] = wsrc[(size_t)(c * 8 + j) * DD + col] * SQ_A;
        uint4 pk;
        pk.x = pk2(v[0], v[1]); pk.y = pk2(v[2], v[3]);
        pk.z = pk2(v[4], v[5]); pk.w = pk2(v[6], v[7]);
        int prow = (col >> 5) * 32 + ((col & 1) << 4) + ((col & 31) >> 1);
        *(uint4*)&wtb[((size_t)seg * DD + prow) * DD + c * 8] = pk;
    } else if (t < PREP_TASKS) {
        int u = t - (PREP_FEAT + PREP_WTB);
        ((int4*)offs)[u] = make_int4(0, 0, 0, 0);
    }
}

// ---------------------------------------------------------------------------
// Histogram.
// ---------------------------------------------------------------------------
__global__ __launch_bounds__(256)
void hist_kernel(const int* __restrict__ dst, int* __restrict__ offs)
{
    int e = blockIdx.x * 256 + threadIdx.x;
    if (e < NE) atomicAdd(&offs[dst[e]], 1);
}

// ---------------------------------------------------------------------------
// Transform: ONE block per 64-node tile computes ALL THREE segs.
// A-frags (16×b128) loaded once from featb, reused across the 3 B-panels.
// wtb rows permuted (see prep) → lane mq owns adjacent cols 2mq,2mq+1 →
// epilogue: 16× packed-uint stores (hrelb) / 16× float2 stores (out).
//   seg 0/1 → hrelb[r] (bf16, sqrt(a) folded into wtb)
//   seg 2   → out = bias + loop message (fp32)
// ---------------------------------------------------------------------------
__global__ __launch_bounds__(256, 3)
void transform_mfma_kernel(const ushort* __restrict__ featb,
                           const ushort* __restrict__ wtb,
                           const float* __restrict__ h_bias,
                           ushort* __restrict__ hrelb,
                           float* __restrict__ out)
{
    const int tile  = blockIdx.x;
    const int node0 = tile * 64;
    const int wv    = threadIdx.x >> 6;
    const int lane  = threadIdx.x & 63;
    const int mq    = lane & 15;
    const int quad  = lane >> 4;
    const int col0  = wv * 32;

    // Load all A fragments once: A[m=mq][k=quad*8+j] per (mt, ks).
    short8 afrag[4][4];
#pragma unroll
    for (int mt = 0; mt < 4; ++mt) {
        const ushort* arow = featb + (size_t)(node0 + mt * 16 + mq) * DD;
#pragma unroll
        for (int ks = 0; ks < 4; ++ks)
            afrag[mt][ks] = *(const short8*)&arow[ks * 32 + quad * 8];
    }

#pragma unroll 1
    for (int seg = 0; seg < 3; ++seg) {
        const ushort* wseg = wtb + (size_t)seg * DD * DD;

        short8 bfrag[2][4];
#pragma unroll
        for (int nt = 0; nt < 2; ++nt)
#pragma unroll
            for (int ks = 0; ks < 4; ++ks)
                bfrag[nt][ks] = *(const short8*)
                    &wseg[(size_t)(col0 + nt * 16 + mq) * DD + ks * 32 + quad * 8];

        float4v acc[4][2];
#pragma unroll
        for (int mt = 0; mt < 4; ++mt)
#pragma unroll
            for (int nt = 0; nt < 2; ++nt)
                acc[mt][nt] = (float4v){0.f, 0.f, 0.f, 0.f};

#pragma unroll
        for (int mt = 0; mt < 4; ++mt)
#pragma unroll
            for (int ks = 0; ks < 4; ++ks)
#pragma unroll
                for (int nt = 0; nt < 2; ++nt)
                    acc[mt][nt] = __builtin_amdgcn_mfma_f32_16x16x32_bf16(
                        afrag[mt][ks], bfrag[nt][ks], acc[mt][nt], 0, 0, 0);

        // Epilogue. D: row = quad*4 + r; lane mq owns cols col0+2mq, +1.
        if (seg < 2) {
            ushort* hb = hrelb + (size_t)seg * NN * DD;
#pragma unroll
            for (int mt = 0; mt < 4; ++mt) {
#pragma unroll
                for (int r = 0; r < 4; ++r) {
                    int node = node0 + mt * 16 + quad * 4 + r;
                    if (node < NN) {
                        uint pk = pk2(acc[mt][0][r], acc[mt][1][r]);
                        *(uint*)&hb[(size_t)node * DD + col0 + 2 * mq] = pk;
                    }
                }
            }
        } else {
            float2 bv = *(const float2*)&h_bias[col0 + 2 * mq];
#pragma unroll
            for (int mt = 0; mt < 4; ++mt) {
#pragma unroll
                for (int r = 0; r < 4; ++r) {
                    int node = node0 + mt * 16 + quad * 4 + r;
                    if (node < NN) {
                        float2 v = make_float2(acc[mt][0][r] + bv.x,
                                               acc[mt][1][r] + bv.y);
                        *(float2*)&out[(size_t)node * DD + col0 + 2 * mq] = v;
                    }
                }
            }
        }
    }
}

// ---------------------------------------------------------------------------
// Parallel scan, two kernels over 49×1024 = OFFS_PAD elements.
// scan_a: per-block sums → csum[49].
// scan_apply: block base = Σ csum[b<bid] (uniform scalar loads), wave scan,
//             apply; writes offs (exclusive) and cursor.
// ---------------------------------------------------------------------------
__global__ __launch_bounds__(1024)
void scan_a_kernel(const int* __restrict__ offs, int* __restrict__ csum)
{
    __shared__ int ws[16];
    int i = blockIdx.x * 1024 + threadIdx.x;
    int v = offs[i];                       // padded region is zeroed
    for (int d = 32; d > 0; d >>= 1) v += __shfl_down(v, d, 64);
    int lane = threadIdx.x & 63, wv = threadIdx.x >> 6;
    if (lane == 0) ws[wv] = v;
    __syncthreads();
    if (threadIdx.x < 16) {
        int s = ws[threadIdx.x];
        for (int d = 8; d > 0; d >>= 1) s += __shfl_down(s, d, 64);
        if (threadIdx.x == 0) csum[blockIdx.x] = s;
    }
}

__global__ __launch_bounds__(1024)
void scan_apply_kernel(int* __restrict__ offs, int* __restrict__ cursor,
                       const int* __restrict__ csum)
{
    __shared__ int ws[16];
    const int bid  = blockIdx.x;
    const int lane = threadIdx.x & 63;
    const int wvi  = threadIdx.x >> 6;

    // Block base: sum of preceding chunk sums (uniform → scalar loads).
    int base = 0;
    for (int b = 0; b < 49; ++b)
        if (b < bid) base += csum[b];

    int i = bid * 1024 + threadIdx.x;
    int v = offs[i];
    int inc = v;
#pragma unroll
    for (int d = 1; d < 64; d <<= 1) {
        int t = __shfl_up(inc, d, 64);
        if (lane >= d) inc += t;
    }
    if (lane == 63) ws[wvi] = inc;
    __syncthreads();
    int wbase = 0;
#pragma unroll
    for (int w = 0; w < 16; ++w) {
        int s = ws[w];
        if (w < wvi) wbase += s;
    }
    int excl = base + wbase + inc - v;
    offs[i] = excl;                        // i == NN gets total (=NE) ✓
    if (i < NN) cursor[i] = excl;
}

// payload[p] = ety*NN + src  → direct hrelb row index for gather.
__global__ __launch_bounds__(256)
void place_kernel(const int* __restrict__ src, const int* __restrict__ dst,
                  const int* __restrict__ ety,
                  int* __restrict__ cursor, int* __restrict__ payload)
{
    int e = blockIdx.x * 256 + threadIdx.x;
    if (e >= NE) return;
    int p = atomicAdd(&cursor[dst[e]], 1);
    payload[p] = ety[e] * NN + src[e];
}

// ---------------------------------------------------------------------------
// Gather: one wave per node; bf16 messages, fp32 accumulate, 4 loads in
// flight. acc starts at out[n] (= bias + loop message).
// ---------------------------------------------------------------------------
__global__ __launch_bounds__(256)
void gather_kernel(const int* __restrict__ offs, const int* __restrict__ payload,
                   const ushort* __restrict__ hrelb, float* __restrict__ out)
{
    const int n = blockIdx.x * 4 + (threadIdx.x >> 6);
    if (n >= NN) return;
    const int lane = threadIdx.x & 63;
    const int e0 = offs[n];
    const int e1 = offs[n + 1];
    float* orow = out + (size_t)n * DD;
    float2 a0 = ((float2*)orow)[lane];
    float2 a1 = make_float2(0.f, 0.f);
    float2 a2 = make_float2(0.f, 0.f);
    float2 a3 = make_float2(0.f, 0.f);
    int e = e0;
    for (; e + 4 <= e1; e += 4) {
        int p0 = payload[e],     p1 = payload[e + 1];
        int p2 = payload[e + 2], p3 = payload[e + 3];
        uint d0 = *(const uint*)&hrelb[(size_t)p0 * DD + lane * 2];
        uint d1 = *(const uint*)&hrelb[(size_t)p1 * DD + lane * 2];
        uint d2 = *(const uint*)&hrelb[(size_t)p2 * DD + lane * 2];
        uint d3 = *(const uint*)&hrelb[(size_t)p3 * DD + lane * 2];
        a0.x += bf_lo(d0); a0.y += bf_hi(d0);
        a1.x += bf_lo(d1); a1.y += bf_hi(d1);
        a2.x += bf_lo(d2); a2.y += bf_hi(d2);
        a3.x += bf_lo(d3); a3.y += bf_hi(d3);
    }
    for (; e < e1; ++e) {
        int p0 = payload[e];
        uint d0 = *(const uint*)&hrelb[(size_t)p0 * DD + lane * 2];
        a0.x += bf_lo(d0); a0.y += bf_hi(d0);
    }
    a0.x += a1.x + a2.x + a3.x;
    a0.y += a1.y + a2.y + a3.y;
    ((float2*)orow)[lane] = a0;
}

// ---------------------------------------------------------------------------
// Tier-2 fallback: atomic scatter from bf16 hrelb.
// ---------------------------------------------------------------------------
__global__ __launch_bounds__(256)
void scatter_kernel(const int* __restrict__ src, const int* __restrict__ dst,
                    const int* __restrict__ ety,
                    const ushort* __restrict__ hrelb,
                    float* __restrict__ out)
{
    const int e = blockIdx.x * 4 + (threadIdx.x >> 6);
    if (e >= NE) return;
    const int lane = threadIdx.x & 63;
    uint d0 = *(const uint*)&hrelb[
        ((size_t)ety[e] * NN + src[e]) * DD + lane * 2];
    float* o = out + (size_t)dst[e] * DD + lane * 2;
    atomicAdd(o,     bf_lo(d0));
    atomicAdd(o + 1, bf_hi(d0));
}

// Tier-3 fallback: fp32 out-init (loop message + bias) + fused per-edge matvec.
__global__ __launch_bounds__(256)
void loop_init_kernel(const float* __restrict__ feat,
                      const float* __restrict__ loop_weight,
                      const float* __restrict__ h_bias,
                      float* __restrict__ out)
{
    const int n = blockIdx.x * 4 + (threadIdx.x >> 6);
    if (n >= NN) return;
    const int lane = threadIdx.x & 63;
    const float2 fv = ((const float2*)(feat + (size_t)n * DD))[lane];
    float a0 = h_bias[lane], a1 = h_bias[lane + 64];
    for (int k = 0; k < 64; ++k) {
        float f0 = __shfl(fv.x, k, 64);
        float f1 = __shfl(fv.y, k, 64);
        a0 += SQ_A * (f0 * loop_weight[(size_t)(2 * k) * DD + lane]
                    + f1 * loop_weight[(size_t)(2 * k + 1) * DD + lane]);
        a1 += SQ_A * (f0 * loop_weight[(size_t)(2 * k) * DD + lane + 64]
                    + f1 * loop_weight[(size_t)(2 * k + 1) * DD + lane + 64]);
    }
    out[(size_t)n * DD + lane] = a0;
    out[(size_t)n * DD + lane + 64] = a1;
}

__global__ __launch_bounds__(256)
void fused_edge_kernel(const float* __restrict__ feat,
                       const int* __restrict__ src, const int* __restrict__ dst,
                       const int* __restrict__ ety,
                       const float* __restrict__ weight,
                       float* __restrict__ out)
{
    const int wave  = threadIdx.x >> 6;
    const int lane  = threadIdx.x & 63;
    const int nwav  = gridDim.x * 4;
    for (int e = blockIdx.x * 4 + wave; e < NE; e += nwav) {
        const int s = src[e];
        const int d = dst[e];
        const int r = ety[e];
        const float2 fv = ((const float2*)(feat + (size_t)s * DD))[lane];
        const float* W = weight + (size_t)r * DD * DD;
        float a0 = 0.f, a1 = 0.f;
        for (int k = 0; k < 64; ++k) {
            float f0 = __shfl(fv.x, k, 64);
            float f1 = __shfl(fv.y, k, 64);
            a0 += f0 * W[(size_t)(2 * k) * DD + lane]
                + f1 * W[(size_t)(2 * k + 1) * DD + lane];
            a1 += f0 * W[(size_t)(2 * k) * DD + lane + 64]
                + f1 * W[(size_t)(2 * k + 1) * DD + lane + 64];
        }
        atomicAdd(out + (size_t)d * DD + lane,      SQ_A * a0);
        atomicAdd(out + (size_t)d * DD + lane + 64, SQ_A * a1);
    }
}

extern "C" void kernel_launch(void* const* d_in, const int* in_sizes, int n_in,
                              void* d_out, int out_size, void* d_ws, size_t ws_size,
                              hipStream_t stream)
{
    const float* feat   = (const float*)d_in[0];
    const int*   src    = (const int*)d_in[1];
    const int*   dst    = (const int*)d_in[2];
    const int*   ety    = (const int*)d_in[3];
    const float* weight = (const float*)d_in[4];
    const float* loop_w = (const float*)d_in[5];
    const float* h_bias = (const float*)d_in[6];
    float* out  = (float*)d_out;

    // Workspace layout (all sections 16B-multiple sized).
    char* p = (char*)d_ws;
    ushort* featb = (ushort*)p;  p += (size_t)NPAD * DD * 2;    // 12.81 MB
    ushort* wtb   = (ushort*)p;  p += (size_t)3 * DD * DD * 2;  // 96 KB
    ushort* hrelb = (ushort*)p;  p += (size_t)2 * NN * DD * 2;  // 25.6 MB
    int* offs     = (int*)p;     p += (size_t)OFFS_PAD * 4;
    const size_t need_t2 = (size_t)(p - (char*)d_ws);
    int* cursor   = (int*)p;     p += (size_t)OFFS_PAD * 4;
    int* csum     = (int*)p;     p += 64 * 4;
    int* payload  = (int*)p;     p += (size_t)NE * 4;
    const size_t need_full = (size_t)(p - (char*)d_ws);         // ~41.2 MB

    if (ws_size >= need_full) {
        prep_kernel<<<(PREP_TASKS + 255) / 256, 256, 0, stream>>>(
            feat, weight, loop_w, featb, wtb, offs);
        hist_kernel<<<(NE + 255) / 256, 256, 0, stream>>>(dst, offs);
        transform_mfma_kernel<<<NTILE, 256, 0, stream>>>(
            featb, wtb, h_bias, hrelb, out);
        scan_a_kernel<<<49, 1024, 0, stream>>>(offs, csum);
        scan_apply_kernel<<<49, 1024, 0, stream>>>(offs, cursor, csum);
        place_kernel<<<(NE + 255) / 256, 256, 0, stream>>>(
            src, dst, ety, cursor, payload);
        gather_kernel<<<(NN + 3) / 4, 256, 0, stream>>>(
            offs, payload, hrelb, out);
    } else if (ws_size >= need_t2) {
        prep_kernel<<<(PREP_TASKS + 255) / 256, 256, 0, stream>>>(
            feat, weight, loop_w, featb, wtb, offs);
        transform_mfma_kernel<<<NTILE, 256, 0, stream>>>(
            featb, wtb, h_bias, hrelb, out);
        scatter_kernel<<<dim3((NE + 3) / 4), 256, 0, stream>>>(
            src, dst, ety, hrelb, out);
    } else {
        loop_init_kernel<<<(NN + 3) / 4, 256, 0, stream>>>(
            feat, loop_w, h_bias, out);
        fused_edge_kernel<<<dim3(2048), 256, 0, stream>>>(
            feat, src, dst, ety, weight, out);
    }
}